// Round 1
// baseline (251.544 us; speedup 1.0000x reference)
//
#include <hip/hip_runtime.h>

#define C_COLS 16

// ---------------------------------------------------------------------------
// Kernel 1: grid-stride reduce. Each thread loads float4 (4 consecutive
// columns). Total threads is a multiple of 4, so a given thread always sees
// the same column group cb = (gid & 3) * 4. Wave-level xor-shuffle reduce
// (lanes with equal lane&3 share a column group), then tiny LDS combine,
// then per-block partials written to ws (deterministic, no global atomics).
// ---------------------------------------------------------------------------
__global__ __launch_bounds__(256) void k_reduce(const float4* __restrict__ x4,
                                                long long n4,
                                                float* __restrict__ partials) {
    const int tid = threadIdx.x;
    const long long gid = (long long)blockIdx.x * blockDim.x + tid;
    const long long stride = (long long)gridDim.x * blockDim.x;  // % 4 == 0

    float s0 = 0.f, s1 = 0.f, s2 = 0.f, s3 = 0.f;
    float c0 = 0.f, c1 = 0.f, c2 = 0.f, c3 = 0.f;

    for (long long i = gid; i < n4; i += stride) {
        float4 v = x4[i];
        bool m0 = (v.x == v.x); s0 += m0 ? v.x : 0.f; c0 += m0 ? 1.f : 0.f;
        bool m1 = (v.y == v.y); s1 += m1 ? v.y : 0.f; c1 += m1 ? 1.f : 0.f;
        bool m2 = (v.z == v.z); s2 += m2 ? v.z : 0.f; c2 += m2 ? 1.f : 0.f;
        bool m3 = (v.w == v.w); s3 += m3 ? v.w : 0.f; c3 += m3 ? 1.f : 0.f;
    }

    // Butterfly over lanes with identical (lane & 3): xor offsets 4,8,16,32.
    for (int off = 4; off < 64; off <<= 1) {
        s0 += __shfl_xor(s0, off, 64);
        s1 += __shfl_xor(s1, off, 64);
        s2 += __shfl_xor(s2, off, 64);
        s3 += __shfl_xor(s3, off, 64);
        c0 += __shfl_xor(c0, off, 64);
        c1 += __shfl_xor(c1, off, 64);
        c2 += __shfl_xor(c2, off, 64);
        c3 += __shfl_xor(c3, off, 64);
    }

    __shared__ float bsum[C_COLS];
    __shared__ float bcnt[C_COLS];
    if (tid < C_COLS) { bsum[tid] = 0.f; bcnt[tid] = 0.f; }
    __syncthreads();

    if ((tid & 63) < 4) {           // lanes 0..3 of each wave hold group totals
        const int cb = (tid & 3) * 4;
        atomicAdd(&bsum[cb + 0], s0);
        atomicAdd(&bsum[cb + 1], s1);
        atomicAdd(&bsum[cb + 2], s2);
        atomicAdd(&bsum[cb + 3], s3);
        atomicAdd(&bcnt[cb + 0], c0);
        atomicAdd(&bcnt[cb + 1], c1);
        atomicAdd(&bcnt[cb + 2], c2);
        atomicAdd(&bcnt[cb + 3], c3);
    }
    __syncthreads();

    if (tid < C_COLS) {
        partials[(long long)blockIdx.x * 32 + tid] = bsum[tid];
        partials[(long long)blockIdx.x * 32 + 16 + tid] = bcnt[tid];
    }
}

// ---------------------------------------------------------------------------
// Kernel 2: single block. Reduce nb partial rows -> mean[16]. Also handles
// any scalar tail (n % 4 != 0 — not hit for this problem, kept for safety).
// ---------------------------------------------------------------------------
__global__ __launch_bounds__(256) void k_final(const float* __restrict__ partials,
                                               int nb,
                                               const float* __restrict__ x,
                                               long long n4, long long n,
                                               float* __restrict__ mean_out) {
    const int tid = threadIdx.x;
    const int c = tid & 15;
    const int r0 = tid >> 4;  // 0..15

    float s = 0.f, cnt = 0.f;
    for (int p = r0; p < nb; p += 16) {
        s   += partials[(long long)p * 32 + c];
        cnt += partials[(long long)p * 32 + 16 + c];
    }

    __shared__ float ssum[256];
    __shared__ float scnt[256];
    ssum[tid] = s;
    scnt[tid] = cnt;
    __syncthreads();

    if (tid < 16) {
        float S = 0.f, Cn = 0.f;
        for (int r = 0; r < 16; ++r) {
            S  += ssum[r * 16 + tid];
            Cn += scnt[r * 16 + tid];
        }
        // scalar tail (elements n4*4 .. n-1), column = j % 16
        for (long long j = n4 * 4; j < n; ++j) {
            if ((int)(j % 16) == tid) {
                float v = x[j];
                if (v == v) { S += v; Cn += 1.f; }
            }
        }
        mean_out[tid] = S / fmaxf(Cn, 1.f);
    }
}

// ---------------------------------------------------------------------------
// Kernel 3: grid-stride fill. Column group per thread is constant (see k1),
// so the 4 mean values are hoisted out of the loop.
// ---------------------------------------------------------------------------
__global__ __launch_bounds__(256) void k_fill(const float4* __restrict__ x4,
                                              float4* __restrict__ o4,
                                              long long n4, long long n,
                                              const float* __restrict__ mean) {
    const int tid = threadIdx.x;
    const long long gid = (long long)blockIdx.x * blockDim.x + tid;
    const long long stride = (long long)gridDim.x * blockDim.x;  // % 4 == 0

    const int cb = (int)(gid & 3) * 4;
    const float m0 = mean[cb + 0];
    const float m1 = mean[cb + 1];
    const float m2 = mean[cb + 2];
    const float m3 = mean[cb + 3];

    for (long long i = gid; i < n4; i += stride) {
        float4 v = x4[i];
        v.x = (v.x == v.x) ? v.x : m0;
        v.y = (v.y == v.y) ? v.y : m1;
        v.z = (v.z == v.z) ? v.z : m2;
        v.w = (v.w == v.w) ? v.w : m3;
        o4[i] = v;
    }

    if (blockIdx.x == 0 && tid == 0) {  // scalar tail (unused for this shape)
        const float* x = (const float*)x4;
        float* o = (float*)o4;
        for (long long j = n4 * 4; j < n; ++j) {
            float v = x[j];
            o[j] = (v == v) ? v : mean[(int)(j % 16)];
        }
    }
}

extern "C" void kernel_launch(void* const* d_in, const int* in_sizes, int n_in,
                              void* d_out, int out_size, void* d_ws, size_t ws_size,
                              hipStream_t stream) {
    const float* x = (const float*)d_in[0];
    float* out = (float*)d_out;
    const long long n = (long long)in_sizes[0];
    const long long n4 = n / 4;

    // ws layout: [nb1 * 32] partial sums/counts, then [16] means.
    int nb1 = 1024;
    {
        long long cap = ((long long)(ws_size / 4) - 16) / 32;
        if (cap < 1) cap = 1;
        if (nb1 > cap) nb1 = (int)cap;
    }
    float* partials = (float*)d_ws;
    float* mean = partials + (long long)nb1 * 32;

    k_reduce<<<nb1, 256, 0, stream>>>((const float4*)x, n4, partials);
    k_final<<<1, 256, 0, stream>>>(partials, nb1, x, n4, n, mean);

    const int nb3 = 2048;
    k_fill<<<nb3, 256, 0, stream>>>((const float4*)x, (float4*)out, n4, n, mean);
}